// Round 3
// baseline (839.231 us; speedup 1.0000x reference)
//
#include <hip/hip_runtime.h>
#include <hip/hip_bf16.h>

// ChildSumTreeLSTM, fp32 in/out, depth=17, N=2^18-1, D_IN=H=128.
// Numerics: split-2 MFMA — weights kept exact as (hi + lo) bf16 pair (2 MFMAs per
// product), activations plain bf16. Weight rounding error (coherent across the
// 17-level c-recurrence) is eliminated; activation rounding is per-node
// independent -> quadrature accumulation ~1e-3 << 0.13 threshold.
// h stored bf16 (halves h traffic); c stored fp32 (long recurrence).
//  k_prep : split 8 weight matrices into hi/lo bf16, pre-swizzled to B-frag order
//  k_leaf : fused x@[Wi|Wo|Wu]+b -> h (bf16), c (fp32)
//  k_level: fused x@W(4 gates) + ht@[Ui|Uo|Uu] + hc@Uf + cell update
//  k_out  : root (h,c) -> d_out (256 fp32)

typedef __bf16 bf16_t;
typedef __bf16 bf16x8 __attribute__((ext_vector_type(8)));
typedef float  f32x4  __attribute__((ext_vector_type(4)));

#define MFMA16(a, b, c) __builtin_amdgcn_mfma_f32_16x16x32_bf16((a), (b), (c), 0, 0, 0)

__device__ __forceinline__ float sigm(float x) { return 1.0f / (1.0f + __expf(-x)); }
__device__ __forceinline__ float tanh_(float x) {
    float a = fabsf(x);
    float e = __expf(2.0f * a);
    float t = 1.0f - 2.0f / (e + 1.0f);
    return copysignf(t, x);
}

// cvt 16 consecutive floats -> bf16, store as two bf16x8 (16B-aligned dest)
__device__ __forceinline__ void cvt16(const float* __restrict__ src, bf16_t* __restrict__ dst)
{
    float tmp[16];
    *(float4*)&tmp[0]  = ((const float4*)src)[0];
    *(float4*)&tmp[4]  = ((const float4*)src)[1];
    *(float4*)&tmp[8]  = ((const float4*)src)[2];
    *(float4*)&tmp[12] = ((const float4*)src)[3];
    bf16_t b[16];
#pragma unroll
    for (int j = 0; j < 16; j++) b[j] = (bf16_t)tmp[j];
    *(bf16x8*)&dst[0] = *(bf16x8*)&b[0];
    *(bf16x8*)&dst[8] = *(bf16x8*)&b[8];
}

// ---------------------------------------------------------------------------
// Swizzled weights, slot s at SW + s*32768: hi[idx], lo = hi+16384,
// idx = ((nt*4+kb)*64 + lane)*8 + j ; element = W[kb*32+(lane>>4)*8+j][nt*16+(lane&15)]
// Slots: 0=Wi 1=Wf 2=Wo 3=Wu 4=Ui 5=Uf 6=Uo 7=Uu
__global__ __launch_bounds__(256)
void k_prep(const float* __restrict__ Wi, const float* __restrict__ Wf,
            const float* __restrict__ Wo, const float* __restrict__ Wu,
            const float* __restrict__ Ui, const float* __restrict__ Uf,
            const float* __restrict__ Uo, const float* __restrict__ Uu,
            bf16_t* __restrict__ SW)
{
    const float* src;
    switch (blockIdx.x) {
        case 0: src = Wi; break; case 1: src = Wf; break;
        case 2: src = Wo; break; case 3: src = Wu; break;
        case 4: src = Ui; break; case 5: src = Uf; break;
        case 6: src = Uo; break; default: src = Uu; break;
    }
    bf16_t* hi = SW + (size_t)blockIdx.x * 32768;
    bf16_t* lo = hi + 16384;
    for (int idx = threadIdx.x; idx < 16384; idx += 256) {
        int j = idx & 7, lane = (idx >> 3) & 63, kb = (idx >> 9) & 3, nt = idx >> 11;
        int k = kb * 32 + (lane >> 4) * 8 + j;
        int n = nt * 16 + (lane & 15);
        float w = src[k * 128 + n];
        bf16_t hh = (bf16_t)w;
        hi[idx] = hh;
        lo[idx] = (bf16_t)(w - (float)hh);
    }
}

// ---------------------------------------------------------------------------
// Leaves: 32/block. acc = x@[Wi|Wo|Wu] (split-2), then i,o,u -> h(bf16), c(fp32).
__global__ __launch_bounds__(256)
void k_leaf(const float* __restrict__ x, int leaf_off,
            const bf16_t* __restrict__ SW,
            const float* __restrict__ bi, const float* __restrict__ bo,
            const float* __restrict__ bu,
            bf16_t* __restrict__ h_out, float* __restrict__ c_out)
{
    __shared__ __align__(16) char smem[25088];
    bf16_t (*A)[136]  = (bf16_t(*)[136])(smem);   //  8704 B (staging)
    float  (*Ch)[196] = (float(*)[196])(smem);    // 25088 B (dump, aliased)

    const int tid = threadIdx.x;
    const int n0  = blockIdx.x * 32;

    {
        int r = tid >> 3, cb = (tid & 7) * 16;
        cvt16(x + (size_t)(leaf_off + n0 + r) * 128 + cb, &A[r][cb]);
    }
    __syncthreads();

    const int wave = tid >> 6, lane = tid & 63;
    const int quad = lane >> 4, lc = lane & 15;

    f32x4 acc[6][2];
#pragma unroll
    for (int nt = 0; nt < 6; nt++)
#pragma unroll
        for (int mt = 0; mt < 2; mt++) acc[nt][mt] = (f32x4){0.f, 0.f, 0.f, 0.f};

    for (int kb = 0; kb < 4; kb++) {
        const int k0 = kb * 32 + quad * 8;
        bf16x8 a0 = *(const bf16x8*)&A[lc][k0];
        bf16x8 a1 = *(const bf16x8*)&A[16 + lc][k0];
#pragma unroll
        for (int nt = 0; nt < 6; nt++) {
            int colb = wave * 96 + nt * 16;
            int g = colb >> 7;                           // 0=i,1=o,2=u
            int slot = (g == 0) ? 0 : (g == 1) ? 2 : 3;  // Wi,Wo,Wu
            const bf16_t* Bh = SW + (size_t)slot * 32768 +
                               ((size_t)((((colb & 127) >> 4)) * 4 + kb) * 64 + lane) * 8;
            bf16x8 bh = *(const bf16x8*)Bh;
            bf16x8 bl = *(const bf16x8*)(Bh + 16384);
            acc[nt][0] = MFMA16(a0, bh, acc[nt][0]);
            acc[nt][0] = MFMA16(a0, bl, acc[nt][0]);
            acc[nt][1] = MFMA16(a1, bh, acc[nt][1]);
            acc[nt][1] = MFMA16(a1, bl, acc[nt][1]);
        }
    }

    for (int p = 0; p < 2; p++) {
        __syncthreads();
#pragma unroll
        for (int nt = 0; nt < 6; nt++) {
            int colb = wave * 96 + nt * 16;
            if (((colb >> 6) & 1) == p) {
                int dst = (colb >> 7) * 64 + (colb & 63);
#pragma unroll
                for (int mt = 0; mt < 2; mt++)
#pragma unroll
                    for (int r = 0; r < 4; r++)
                        Ch[mt * 16 + quad * 4 + r][dst + lc] = acc[nt][mt][r];
            }
        }
        __syncthreads();
        for (int idx = tid; idx < 32 * 64; idx += 256) {
            int m = idx >> 6, jj = idx & 63, j = p * 64 + jj;
            float iv = sigm(Ch[m][jj] + bi[j]);
            float ov = sigm(Ch[m][64 + jj] + bo[j]);
            float uv = tanh_(Ch[m][128 + jj] + bu[j]);
            float cv = iv * uv;
            float hv = ov * tanh_(cv);
            size_t node = (size_t)(n0 + m);
            h_out[node * 128 + j] = (bf16_t)hv;
            c_out[node * 128 + j] = cv;
        }
    }
}

// ---------------------------------------------------------------------------
// One tree level: 32 parents/block. Wave gates: w0=i w1=f w2=o w3=u.
__global__ __launch_bounds__(256)
void k_level(const float* __restrict__ x, const bf16_t* __restrict__ SW,
             const float* __restrict__ bi, const float* __restrict__ bf_,
             const float* __restrict__ bo, const float* __restrict__ bu,
             const bf16_t* __restrict__ h_in, const float* __restrict__ c_in,
             bf16_t* __restrict__ h_out, float* __restrict__ c_out,
             int sl, int nl)
{
    __shared__ __align__(16) char smem[34816];
    bf16_t (*X)[136]  = (bf16_t(*)[136])(smem);            //  8704 B staging
    bf16_t (*HC)[136] = (bf16_t(*)[136])(smem + 8704);     // 17408 B staging
    bf16_t (*HT)[136] = (bf16_t(*)[136])(smem + 26112);    //  8704 B staging
    float  (*C1q)[100] = (float(*)[100])(smem);            // 12800 B dump (alias)
    float  (*XFq)[36]  = (float(*)[36])(smem + 12800);     //  4608 B dump (alias)
    float  (*C2q)[36]  = (float(*)[36])(smem + 17408);     //  9216 B dump (alias)

    const int tid = threadIdx.x;
    const int n0  = blockIdx.x * 32;

    {   // stage x rows of the 32 parents (fp32 -> bf16)
        int r = tid >> 3, cb = (tid & 7) * 16;
        cvt16(x + (size_t)(sl + n0 + r) * 128 + cb, &X[r][cb]);
    }
    {   // stage 64 children h rows (bf16 raw copy), zero beyond level
        int r = tid >> 2, cb = (tid & 3) * 32;
        int row = 2 * n0 + r;
        if (row < 2 * nl) {
            const uint4* src = (const uint4*)(h_in + (size_t)row * 128 + cb);
            *(uint4*)&HC[r][cb]      = src[0];
            *(uint4*)&HC[r][cb + 8]  = src[1];
            *(uint4*)&HC[r][cb + 16] = src[2];
            *(uint4*)&HC[r][cb + 24] = src[3];
        } else {
            uint4 z = {0u, 0u, 0u, 0u};
            *(uint4*)&HC[r][cb]      = z;
            *(uint4*)&HC[r][cb + 8]  = z;
            *(uint4*)&HC[r][cb + 16] = z;
            *(uint4*)&HC[r][cb + 24] = z;
        }
    }
    __syncthreads();
    // child-sum HT = HC[2m] + HC[2m+1] (fp32 add, bf16 store), once
    for (int ci = tid; ci < 512; ci += 256) {
        int m = ci >> 4, j0 = (ci & 15) * 8;
        bf16x8 h0 = *(const bf16x8*)&HC[2 * m][j0];
        bf16x8 h1 = *(const bf16x8*)&HC[2 * m + 1][j0];
        bf16_t s[8];
#pragma unroll
        for (int j = 0; j < 8; j++) s[j] = (bf16_t)((float)h0[j] + (float)h1[j]);
        *(bf16x8*)&HT[m][j0] = *(bf16x8*)&s[0];
    }
    __syncthreads();

    const int wave = tid >> 6, lane = tid & 63;
    const int quad = lane >> 4, lc = lane & 15;

    const bf16_t* Wh = SW + (size_t)wave * 32768;
    const bf16_t* Uh = nullptr;
    if (wave != 1) {
        int us = (wave == 0) ? 4 : (wave == 2) ? 6 : 7;
        Uh = SW + (size_t)us * 32768;
    }
    const bf16_t* Fh = SW + (size_t)5 * 32768;

    f32x4 accM[8][2];
    f32x4 accF[2][4];
#pragma unroll
    for (int nt = 0; nt < 8; nt++)
#pragma unroll
        for (int mt = 0; mt < 2; mt++) accM[nt][mt] = (f32x4){0.f, 0.f, 0.f, 0.f};
#pragma unroll
    for (int t = 0; t < 2; t++)
#pragma unroll
        for (int mt = 0; mt < 4; mt++) accF[t][mt] = (f32x4){0.f, 0.f, 0.f, 0.f};

    for (int kb = 0; kb < 4; kb++) {
        const int k0 = kb * 32 + quad * 8;
        bf16x8 xa0 = *(const bf16x8*)&X[lc][k0];
        bf16x8 xa1 = *(const bf16x8*)&X[16 + lc][k0];
        bf16x8 ta0 = *(const bf16x8*)&HT[lc][k0];
        bf16x8 ta1 = *(const bf16x8*)&HT[16 + lc][k0];
#pragma unroll
        for (int nt = 0; nt < 8; nt++) {
            const size_t boff = ((size_t)(nt * 4 + kb) * 64 + lane) * 8;
            bf16x8 bWh = *(const bf16x8*)(Wh + boff);
            bf16x8 bWl = *(const bf16x8*)(Wh + 16384 + boff);
            accM[nt][0] = MFMA16(xa0, bWh, accM[nt][0]);
            accM[nt][0] = MFMA16(xa0, bWl, accM[nt][0]);
            accM[nt][1] = MFMA16(xa1, bWh, accM[nt][1]);
            accM[nt][1] = MFMA16(xa1, bWl, accM[nt][1]);
            if (wave != 1) {
                bf16x8 bUh = *(const bf16x8*)(Uh + boff);
                bf16x8 bUl = *(const bf16x8*)(Uh + 16384 + boff);
                accM[nt][0] = MFMA16(ta0, bUh, accM[nt][0]);
                accM[nt][0] = MFMA16(ta0, bUl, accM[nt][0]);
                accM[nt][1] = MFMA16(ta1, bUh, accM[nt][1]);
                accM[nt][1] = MFMA16(ta1, bUl, accM[nt][1]);
            }
        }
        bf16x8 a4[4];
#pragma unroll
        for (int mt = 0; mt < 4; mt++) a4[mt] = *(const bf16x8*)&HC[mt * 16 + lc][k0];
#pragma unroll
        for (int t = 0; t < 2; t++) {
            const size_t boff = ((size_t)((2 * wave + t) * 4 + kb) * 64 + lane) * 8;
            bf16x8 bFh = *(const bf16x8*)(Fh + boff);
            bf16x8 bFl = *(const bf16x8*)(Fh + 16384 + boff);
#pragma unroll
            for (int mt = 0; mt < 4; mt++) {
                accF[t][mt] = MFMA16(a4[mt], bFh, accF[t][mt]);
                accF[t][mt] = MFMA16(a4[mt], bFl, accF[t][mt]);
            }
        }
    }

    // 4-phase epilogue over j-quarters (32 cols each)
    for (int p = 0; p < 4; p++) {
        __syncthreads();   // p0: all staging reads done (dump aliases); p>0: prev epi done
        if (wave != 1) {
            int gi = (wave == 0) ? 0 : (wave == 2) ? 1 : 2;
#pragma unroll
            for (int q = 0; q < 2; q++) {
                int nt = 2 * p + q;
#pragma unroll
                for (int mt = 0; mt < 2; mt++)
#pragma unroll
                    for (int r = 0; r < 4; r++)
                        C1q[mt * 16 + quad * 4 + r][gi * 32 + q * 16 + lc] = accM[nt][mt][r];
            }
        } else {
#pragma unroll
            for (int q = 0; q < 2; q++) {
                int nt = 2 * p + q;
#pragma unroll
                for (int mt = 0; mt < 2; mt++)
#pragma unroll
                    for (int r = 0; r < 4; r++)
                        XFq[mt * 16 + quad * 4 + r][q * 16 + lc] = accM[nt][mt][r];
            }
        }
        if (wave == p) {   // wave p owns f-cols [32p, 32p+32)
#pragma unroll
            for (int t = 0; t < 2; t++)
#pragma unroll
                for (int mt = 0; mt < 4; mt++)
#pragma unroll
                    for (int r = 0; r < 4; r++)
                        C2q[mt * 16 + quad * 4 + r][t * 16 + lc] = accF[t][mt][r];
        }
        __syncthreads();
        for (int idx = tid; idx < 32 * 32; idx += 256) {
            int m = idx >> 5, jj = idx & 31, j = p * 32 + jj;
            int node = n0 + m;
            if (node < nl) {
                float iv = sigm(C1q[m][jj] + bi[j]);
                float ov = sigm(C1q[m][32 + jj] + bo[j]);
                float uv = tanh_(C1q[m][64 + jj] + bu[j]);
                float xf = XFq[m][jj] + bf_[j];
                float f0 = sigm(xf + C2q[2 * m][jj]);
                float f1 = sigm(xf + C2q[2 * m + 1][jj]);
                float cc0 = c_in[(size_t)(2 * node) * 128 + j];
                float cc1 = c_in[(size_t)(2 * node + 1) * 128 + j];
                float cv = iv * uv + f0 * cc0 + f1 * cc1;
                h_out[(size_t)node * 128 + j] = (bf16_t)(ov * tanh_(cv));
                c_out[(size_t)node * 128 + j] = cv;
            }
        }
    }
}

__global__ __launch_bounds__(256)
void k_out(const bf16_t* __restrict__ h, const float* __restrict__ c,
           float* __restrict__ out)
{
    int t = threadIdx.x;
    if (t < 128)      out[t] = (float)h[t];
    else if (t < 256) out[t] = c[t - 128];
}

// ---------------------------------------------------------------------------
extern "C" void kernel_launch(void* const* d_in, const int* in_sizes, int n_in,
                              void* d_out, int out_size, void* d_ws, size_t ws_size,
                              hipStream_t stream)
{
    const float* x   = (const float*)d_in[0];
    const float* Wi  = (const float*)d_in[1];
    const float* bi  = (const float*)d_in[2];
    const float* Ui  = (const float*)d_in[3];
    const float* Wf  = (const float*)d_in[4];
    const float* bf_ = (const float*)d_in[5];
    const float* Uf  = (const float*)d_in[6];
    const float* Wo  = (const float*)d_in[7];
    const float* bo  = (const float*)d_in[8];
    const float* Uo  = (const float*)d_in[9];
    const float* Wu  = (const float*)d_in[10];
    const float* bu  = (const float*)d_in[11];
    const float* Uu  = (const float*)d_in[12];

    int Nn    = in_sizes[0] / 128;
    int depth = 31 - __builtin_clz((unsigned)(Nn + 1)) - 1;
    int NL    = 1 << depth;
    int Mint  = NL - 1;

    // workspace: 512 KB weights + h0,h1 (bf16) + c0,c1 (fp32) = ~202 MiB @ depth 17
    bf16_t* SW = (bf16_t*)d_ws;
    bf16_t* h0 = (bf16_t*)((char*)d_ws + 524288);
    bf16_t* h1 = h0 + (size_t)NL * 128;
    float*  c0 = (float*)(h1 + (size_t)NL * 128);
    float*  c1 = c0 + (size_t)NL * 128;

    k_prep<<<8, 256, 0, stream>>>(Wi, Wf, Wo, Wu, Ui, Uf, Uo, Uu, SW);
    k_leaf<<<NL / 32, 256, 0, stream>>>(x, Mint, SW, bi, bo, bu, h0, c0);

    const bf16_t* hin = h0; const float* cin = c0;
    bf16_t* hout = h1;      float* cout = c1;
    for (int l = depth - 1; l >= 0; --l) {
        int nl = 1 << l, sl = nl - 1;
        int blocks = (nl + 31) / 32;
        k_level<<<blocks, 256, 0, stream>>>(x, SW, bi, bf_, bo, bu,
                                            hin, cin, hout, cout, sl, nl);
        const bf16_t* th = hin; hin = hout; hout = (bf16_t*)th;
        const float*  tc = cin; cin = cout; cout = (float*)tc;
    }
    k_out<<<1, 256, 0, stream>>>(hin, cin, (float*)d_out);
}